// Round 15
// baseline (428.081 us; speedup 1.0000x reference)
//
#include <hip/hip_runtime.h>
#include <math.h>

#define SS 4096      // H*W
#define NE 4194304   // B*C*H*W

typedef __attribute__((ext_vector_type(8))) short short8;
typedef __attribute__((ext_vector_type(4))) short short4v;
typedef __attribute__((ext_vector_type(4))) float f32x4;
typedef __attribute__((ext_vector_type(16))) float f32x16;

__device__ __forceinline__ float wave_sum(float v) {
#pragma unroll
  for (int off = 32; off > 0; off >>= 1) v += __shfl_xor(v, off, 64);
  return v;
}
__device__ __forceinline__ float silu_f(float y) { return y / (1.f + __expf(-y)); }

__device__ __forceinline__ unsigned short to_bf(float x) {
  union { float f; unsigned u; } v; v.f = x;
  unsigned r = v.u + 0x7FFFu + ((v.u >> 16) & 1u);
  return (unsigned short)(r >> 16);
}
__device__ __forceinline__ float bf2f(short s) {
  union { unsigned u; float f; } v;
  v.u = ((unsigned)(unsigned short)s) << 16;
  return v.f;
}

// ---------- fused GN (+ optional SiLU) + bf16 + transpose -> out[b][s][c]
// stats are RAW sums (s, sq); finalized inline.
template <int DO_SILU>
__global__ __launch_bounds__(256) void gn_t_k(const float* __restrict__ x,
    const float* __restrict__ stats, const float* __restrict__ sc,
    const float* __restrict__ bi, short* __restrict__ G) {
  __shared__ short T[64][72];
  const int tid = threadIdx.x;
  const int st = blockIdx.x & 63;
  const int ct = (blockIdx.x >> 6) & 3;
  const int b = blockIdx.x >> 8;
  const int s0 = st * 64, c0 = ct * 64;
#pragma unroll
  for (int r = 0; r < 4; ++r) {
    int idx = r * 256 + tid;
    int c_l = idx >> 4, s4 = idx & 15;
    int c = c0 + c_l;
    int sidx = (b * 32 + (c >> 3)) * 2;
    float ssum = stats[sidx], qsum = stats[sidx + 1];
    float m = ssum * (1.f / 32768.f);
    float var = qsum * (1.f / 32768.f) - m * m;
    float rs = rsqrtf(var + 1e-5f);
    float a = sc[c] * rs;
    float t = bi[c] - m * a;
    float4 v = *(const float4*)(x + ((size_t)(b * 256 + c)) * 4096 + s0 + s4 * 4);
    float o0 = v.x * a + t, o1 = v.y * a + t, o2 = v.z * a + t, o3 = v.w * a + t;
    if (DO_SILU) { o0 = silu_f(o0); o1 = silu_f(o1); o2 = silu_f(o2); o3 = silu_f(o3); }
    T[s4 * 4 + 0][c_l] = (short)to_bf(o0);
    T[s4 * 4 + 1][c_l] = (short)to_bf(o1);
    T[s4 * 4 + 2][c_l] = (short)to_bf(o2);
    T[s4 * 4 + 3][c_l] = (short)to_bf(o3);
  }
  __syncthreads();
#pragma unroll
  for (int r = 0; r < 2; ++r) {
    int idx = r * 256 + tid;
    int s_l = idx >> 3, cg = idx & 7;
    *(short8*)(G + ((size_t)(b * 4096 + s0 + s_l)) * 256 + c0 + cg * 8) =
        *(const short8*)&T[s_l][cg * 8];
  }
}

// ---------- merged prep: wprep x2 | wcast qkv | wcast out | FiLM |
// gn_stats(x) RAW (128 blks) | zero atomic stats buffers (1 blk)
__global__ __launch_bounds__(256) void prep_k(
    const float* __restrict__ conv1_w, const float* __restrict__ conv2_w,
    const float* __restrict__ qkv_w, const float* __restrict__ out_w,
    const float* __restrict__ te, const float* __restrict__ mlp_w,
    const float* __restrict__ mlp_b, const float* __restrict__ x,
    short* __restrict__ Wt1, short* __restrict__ Wt2, short* __restrict__ wqb,
    short* __restrict__ wob, float* __restrict__ gbuf,
    float* __restrict__ stats) {
  const int bid = blockIdx.x, tid = threadIdx.x;
  if (bid < 512) {
    __shared__ short L[9][256];
    const float* w = (bid < 256) ? conv1_w : conv2_w;
    short* wt = (bid < 256) ? Wt1 : Wt2;
    const int oc = bid & 255;
    const float* wp = w + (size_t)oc * 2304;
    for (int i = tid; i < 2304; i += 256) {
      int ic = i / 9, t = i - ic * 9;
      L[t][ic] = (short)to_bf(wp[i]);
    }
    __syncthreads();
    for (int i = tid; i < 2304; i += 256) {
      int t = i >> 8, ic = i & 255;
      wt[((size_t)(t * 256 + oc)) * 256 + ic] = L[t][ic];
    }
  } else if (bid < 1280) {
    int row = bid - 512;
    float sc = (row < 256) ? 0.0625f : 1.f;
    wqb[(size_t)row * 256 + tid] = (short)to_bf(qkv_w[(size_t)row * 256 + tid] * sc);
  } else if (bid < 1536) {
    int row = bid - 1280;
    wob[(size_t)row * 256 + tid] = (short)to_bf(out_w[(size_t)row * 256 + tid]);
  } else if (bid < 1544) {
    int t2 = (bid - 1536) * 256 + tid;
    int b = t2 >> 9, jj = t2 & 511;
    const float* tp = te + b * 256;
    const float* wp = mlp_w + jj * 256;
    float acc = mlp_b[jj];
    for (int t = 0; t < 256; ++t) acc += silu_f(tp[t]) * wp[t];
    gbuf[t2] = acc;
  } else if (bid < 1672) {
    // gn_stats of x (raw sums) for one (b,group)
    const int sub = bid - 1544;
    const float4* p = (const float4*)(x + (size_t)sub * 32768);
    float s = 0.f, q = 0.f;
    for (int i = tid; i < 8192; i += 256) {
      float4 v = p[i];
      s += v.x + v.y + v.z + v.w;
      q += v.x * v.x + v.y * v.y + v.z * v.z + v.w * v.w;
    }
    s = wave_sum(s); q = wave_sum(q);
    __shared__ float red[8];
    int wid = tid >> 6;
    if ((tid & 63) == 0) { red[wid] = s; red[wid + 4] = q; }
    __syncthreads();
    if (tid == 0) {
      stats[sub * 2] = red[0] + red[1] + red[2] + red[3];
      stats[sub * 2 + 1] = red[4] + red[5] + red[6] + red[7];
    }
  } else {
    // zero the atomic raw-stat buffers (stats2 + statsA = 512 floats)
    stats[256 + tid] = 0.f;
    stats[512 + tid] = 0.f;
  }
}

__device__ __forceinline__ short8 ld2x4(const short* p) {
  short4v lo = *(const short4v*)p;
  short4v hi = *(const short4v*)(p + 4);
  short8 r;
  r[0] = lo[0]; r[1] = lo[1]; r[2] = lo[2]; r[3] = lo[3];
  r[4] = hi[0]; r[5] = hi[1]; r[6] = hi[2]; r[7] = hi[3];
  return r;
}

// ---------- MFMA 3x3 conv (R13: 512 blocks of 32oc x 256sp) + fused raw
// GN-stats of its OUTPUT (wave-reduce + 8 atomicAdds per wave; group is
// wave-uniform per i-quad since oc = oc0 + (i&3)+8*(i>>2)+4*hf).
template <int MODE>
__global__ __launch_bounds__(256, 1) void conv_mfma_k(
    const short* __restrict__ G, const short* __restrict__ Wt,
    const float* __restrict__ bias, const float* __restrict__ gb,
    const float* __restrict__ resid, float* __restrict__ out,
    float* __restrict__ sraw) {
  __shared__ __align__(16) short Xs[6][66][36];
  __shared__ __align__(16) short Ws[9][32][32];
  const int tid = threadIdx.x;
  const int oc0 = (blockIdx.x & 7) * 32;
  const int oy = ((blockIdx.x >> 3) & 15) * 4;
  const int b = blockIdx.x >> 7;
  const int wv = tid >> 6, lane = tid & 63;
  const int ln = lane & 31, hf = lane >> 5;

  f32x16 O0 = {}, O1 = {};

  for (int ic0 = 0; ic0 < 256; ic0 += 32) {
    __syncthreads();
    for (int i = tid; i < 1584; i += 256) {
      int r = i / 264;
      int rem = i - r * 264;
      int col = rem >> 2, g = rem & 3;
      int gy = oy + r - 1, gx = col - 1;
      short4v lo = {0, 0, 0, 0}, hi = {0, 0, 0, 0};
      if ((unsigned)gy < 64u && (unsigned)gx < 64u) {
        const short* gp = G + ((size_t)(b * 4096 + gy * 64 + gx)) * 256 + ic0 + g * 8;
        lo = *(const short4v*)gp;
        hi = *(const short4v*)(gp + 4);
      }
      *(short4v*)&Xs[r][col][g * 8] = lo;
      *(short4v*)&Xs[r][col][g * 8 + 4] = hi;
    }
    for (int i = tid; i < 1152; i += 256) {
      int t = i >> 7;
      int rem = i & 127;
      int o = rem >> 2, g = rem & 3;
      *(short8*)&Ws[t][o][g * 8] =
          *(const short8*)(Wt + ((size_t)(t * 256 + oc0 + o)) * 256 + ic0 + g * 8);
    }
    __syncthreads();
    for (int t = 0; t < 9; ++t) {
      const int dy = t / 3, dx = t - dy * 3;
      const short* xrow = &Xs[wv + dy][0][0];
#pragma unroll
      for (int ks = 0; ks < 2; ++ks) {
        short8 a0 = *(const short8*)&Ws[t][ln][ks * 16 + hf * 8];
        short8 b0 = ld2x4(xrow + (ln + dx) * 36 + ks * 16 + hf * 8);
        short8 b1 = ld2x4(xrow + (32 + ln + dx) * 36 + ks * 16 + hf * 8);
        O0 = __builtin_amdgcn_mfma_f32_32x32x16_bf16(a0, b0, O0, 0, 0, 0);
        O1 = __builtin_amdgcn_mfma_f32_32x32x16_bf16(a0, b1, O1, 0, 0, 0);
      }
    }
  }
  const int srow = (oy + wv) * 64;
  float gs[4] = {0.f, 0.f, 0.f, 0.f}, gq[4] = {0.f, 0.f, 0.f, 0.f};
#pragma unroll
  for (int i = 0; i < 16; ++i) {
    int oc = oc0 + (i & 3) + 8 * (i >> 2) + 4 * hf;
    float bi = bias[oc];
    size_t base = ((size_t)(b * 256 + oc)) * 4096 + srow;
    float v0 = O0[i] + bi, v1 = O1[i] + bi;
    if (MODE == 0) {
      float ga = 1.f + gb[b * 512 + oc], be = gb[b * 512 + 256 + oc];
      v0 = ga * v0 + be;
      v1 = ga * v1 + be;
    } else {
      v0 += resid[base + ln];
      v1 += resid[base + 32 + ln];
    }
    out[base + ln] = v0;
    out[base + 32 + ln] = v1;
    int jg = i >> 2;
    gs[jg] += v0 + v1;
    gq[jg] += v0 * v0 + v1 * v1;
  }
  // fused raw GN stats of this output tile
#pragma unroll
  for (int jg = 0; jg < 4; ++jg) {
    float s = wave_sum(gs[jg]);
    float q = wave_sum(gq[jg]);
    if (lane == 0) {
      int gidx = (b * 32 + (oc0 >> 3) + jg) * 2;
      atomicAdd(&sraw[gidx], s);
      atomicAdd(&sraw[gidx + 1], q);
    }
  }
}

// ---------- 1x1 GEMM (MFMA)
template <int MODE>
__global__ __launch_bounds__(256, 2) void gemm1x1_k(
    const short* __restrict__ X, const short* __restrict__ W,
    const float* __restrict__ bias, const float* __restrict__ ml,
    short* __restrict__ q, short* __restrict__ k, short* __restrict__ v,
    float* __restrict__ out) {
  __shared__ __align__(16) short sh[18432];
  const int tid = threadIdx.x;
  const int o0 = blockIdx.x * 64;
  const int s0 = blockIdx.y * 256;
  const int b = blockIdx.z;
  const int w = tid >> 6, lane = tid & 63, ln = lane & 31, hf = lane >> 5;
  {
    const int o = tid >> 2, g = tid & 3;
#pragma unroll
    for (int j = 0; j < 8; ++j) {
      int c = (g * 8 + j) * 8;
      *(short8*)&sh[o * 264 + c] = *(const short8*)(W + (size_t)(o0 + o) * 256 + c);
    }
  }
  __syncthreads();
  f32x16 acc[2][2] = {{{}, {}}, {{}, {}}};
  if (MODE == 0) {
    const short* xp = X + ((size_t)(b * 4096 + s0 + w * 64)) * 256;
    short8 bf0 = *(const short8*)(xp + (size_t)ln * 256 + hf * 8);
    short8 bf1 = *(const short8*)(xp + (size_t)(32 + ln) * 256 + hf * 8);
#pragma unroll
    for (int ks = 0; ks < 16; ++ks) {
      short8 a0 = *(const short8*)&sh[ln * 264 + ks * 16 + hf * 8];
      short8 a1 = *(const short8*)&sh[(32 + ln) * 264 + ks * 16 + hf * 8];
      short8 nb0 = bf0, nb1 = bf1;
      if (ks < 15) {
        nb0 = *(const short8*)(xp + (size_t)ln * 256 + (ks + 1) * 16 + hf * 8);
        nb1 = *(const short8*)(xp + (size_t)(32 + ln) * 256 + (ks + 1) * 16 + hf * 8);
      }
      acc[0][0] = __builtin_amdgcn_mfma_f32_32x32x16_bf16(a0, bf0, acc[0][0], 0, 0, 0);
      acc[0][1] = __builtin_amdgcn_mfma_f32_32x32x16_bf16(a0, bf1, acc[0][1], 0, 0, 0);
      acc[1][0] = __builtin_amdgcn_mfma_f32_32x32x16_bf16(a1, bf0, acc[1][0], 0, 0, 0);
      acc[1][1] = __builtin_amdgcn_mfma_f32_32x32x16_bf16(a1, bf1, acc[1][1], 0, 0, 0);
      bf0 = nb0; bf1 = nb1;
    }
  } else {
    const size_t r0 = (size_t)b * 4096 + s0 + w * 64 + ln;
    const size_t r1 = r0 + 32;
    float inv0 = 1.f / (ml[r0] + ml[16384 + r0] + ml[32768 + r0] + ml[49152 + r0]);
    float inv1 = 1.f / (ml[r1] + ml[16384 + r1] + ml[32768 + r1] + ml[49152 + r1]);
#pragma unroll 4
    for (int ks = 0; ks < 16; ++ks) {
      float t0[8] = {0, 0, 0, 0, 0, 0, 0, 0}, t1[8] = {0, 0, 0, 0, 0, 0, 0, 0};
#pragma unroll
      for (int z = 0; z < 4; ++z) {
        short8 p0 = *(const short8*)(X + ((size_t)z * 16384 + r0) * 256 + ks * 16 + hf * 8);
        short8 p1 = *(const short8*)(X + ((size_t)z * 16384 + r1) * 256 + ks * 16 + hf * 8);
#pragma unroll
        for (int jj = 0; jj < 8; ++jj) { t0[jj] += bf2f(p0[jj]); t1[jj] += bf2f(p1[jj]); }
      }
      short8 bf0, bf1;
#pragma unroll
      for (int jj = 0; jj < 8; ++jj) {
        bf0[jj] = (short)to_bf(t0[jj] * inv0);
        bf1[jj] = (short)to_bf(t1[jj] * inv1);
      }
      short8 a0 = *(const short8*)&sh[ln * 264 + ks * 16 + hf * 8];
      short8 a1 = *(const short8*)&sh[(32 + ln) * 264 + ks * 16 + hf * 8];
      acc[0][0] = __builtin_amdgcn_mfma_f32_32x32x16_bf16(a0, bf0, acc[0][0], 0, 0, 0);
      acc[0][1] = __builtin_amdgcn_mfma_f32_32x32x16_bf16(a0, bf1, acc[0][1], 0, 0, 0);
      acc[1][0] = __builtin_amdgcn_mfma_f32_32x32x16_bf16(a1, bf0, acc[1][0], 0, 0, 0);
      acc[1][1] = __builtin_amdgcn_mfma_f32_32x32x16_bf16(a1, bf1, acc[1][1], 0, 0, 0);
    }
  }
  if (MODE == 1) {
#pragma unroll
    for (int os = 0; os < 2; ++os)
#pragma unroll
      for (int ss = 0; ss < 2; ++ss)
#pragma unroll
        for (int i = 0; i < 16; ++i) {
          int oc = o0 + os * 32 + (i & 3) + 8 * (i >> 2) + 4 * hf;
          size_t idx = ((size_t)(b * 256 + oc)) * 4096 + s0 + w * 64 + ss * 32 + ln;
          out[idx] = out[idx] + acc[os][ss][i] + bias[oc];
        }
  } else if (o0 >= 512) {
#pragma unroll
    for (int os = 0; os < 2; ++os)
#pragma unroll
      for (int ss = 0; ss < 2; ++ss)
#pragma unroll
        for (int i = 0; i < 16; ++i) {
          int oc = (o0 - 512) + os * 32 + (i & 3) + 8 * (i >> 2) + 4 * hf;
          v[((size_t)(b * 256 + oc)) * 4096 + s0 + w * 64 + ss * 32 + ln] =
              (short)to_bf(acc[os][ss][i]);
        }
  } else {
    __syncthreads();
#pragma unroll
    for (int os = 0; os < 2; ++os)
#pragma unroll
      for (int ss = 0; ss < 2; ++ss)
#pragma unroll
        for (int i = 0; i < 16; ++i) {
          int o_l = os * 32 + (i & 3) + 8 * (i >> 2) + 4 * hf;
          int s_l = ss * 32 + ln;
          sh[(w * 64 + s_l) * 72 + o_l] = (short)to_bf(acc[os][ss][i]);
        }
    __syncthreads();
    short* dst = (o0 < 256) ? q : k;
    const int co = (o0 < 256) ? o0 : o0 - 256;
    const short* src = &sh[(w * 64 + lane) * 72];
    short* gp = dst + ((size_t)(b * 4096 + s0 + w * 64 + lane)) * 256 + co;
#pragma unroll
    for (int j = 0; j < 8; ++j)
      *(short8*)(gp + j * 8) = *(const short8*)(src + j * 8);
  }
}

// ---------- MFMA flash attention (R9/R13, measured 108us): 16x16x32,
// q-tile 64, Q in LDS (pad 268), V staged via LDS, K direct from global.
// KEEP (256,2): >=3 spills (R4/R5). 32x32 variants were L2-request-bound.
__global__ __launch_bounds__(256, 2) void attn_k(const short* __restrict__ qb,
    const short* __restrict__ kb, const short* __restrict__ vb,
    short* __restrict__ part, float* __restrict__ ml) {
  __shared__ __align__(16) short qls[64 * 268];
  __shared__ __align__(16) short vls[256 * 68];
  __shared__ __align__(16) short pls[64 * 68];
  __shared__ __align__(16) float lss[64 * 4];
  const int tid = threadIdx.x;
  const int j = blockIdx.x & 7;
  const int b = j >> 1;
  const int idx = ((blockIdx.x >> 3) << 1) | (j & 1);  // 0..255
  const int z = idx >> 6;
  const int s0 = (idx & 63) * 64;
  const int kv0 = z * 1024;
  const int w = tid >> 6, lane = tid & 63, ln = lane & 15, qd = lane >> 4;

  {
    const short* qsrc = qb + ((size_t)(b * 4096 + s0)) * 256;
    for (int i = tid; i < 2048; i += 256) {
      int r = i >> 5, cc = i & 31;
      *(short8*)&qls[r * 268 + cc * 8] = *(const short8*)(qsrc + (size_t)r * 256 + cc * 8);
    }
  }
  const f32x4 z4 = {0.f, 0.f, 0.f, 0.f};
  f32x4 O[4][4];
#pragma unroll
  for (int g = 0; g < 4; ++g)
#pragma unroll
    for (int cs = 0; cs < 4; ++cs) O[g][cs] = z4;
  float l_loc[4] = {0.f, 0.f, 0.f, 0.f};

  const short* kbb = kb + ((size_t)(b * 4096 + kv0)) * 256;
  const short* vbb = vb + ((size_t)b * 256) * 4096 + kv0;

  const int vr = tid >> 3;
  const int vc = (tid & 7) * 8;

  short8 kreg[8], vreg[8];
#pragma unroll
  for (int ks = 0; ks < 8; ++ks)
    kreg[ks] = *(const short8*)(kbb + ((size_t)(w * 16 + ln)) * 256 + ks * 32 + qd * 8);
#pragma unroll
  for (int p = 0; p < 8; ++p)
    vreg[p] = *(const short8*)(vbb + ((size_t)(vr + p * 32)) * 4096 + vc);
  __syncthreads();  // Q staged

  for (int t0 = 0; t0 < 1024; t0 += 64) {
    const int tn = (t0 + 64 < 1024) ? t0 + 64 : t0;
#pragma unroll
    for (int p = 0; p < 8; ++p)
      *(short8*)&vls[(vr + p * 32) * 68 + vc] = vreg[p];
#pragma unroll
    for (int p = 0; p < 8; ++p)
      vreg[p] = *(const short8*)(vbb + ((size_t)(vr + p * 32)) * 4096 + tn + vc);
    f32x4 S[4] = {z4, z4, z4, z4};
#pragma unroll
    for (int ks = 0; ks < 8; ++ks) {
#pragma unroll
      for (int g = 0; g < 4; ++g) {
        short8 qf = *(const short8*)&qls[(g * 16 + ln) * 268 + ks * 32 + qd * 8];
        S[g] = __builtin_amdgcn_mfma_f32_16x16x32_bf16(kreg[ks], qf, S[g], 0, 0, 0);
      }
    }
#pragma unroll
    for (int ks = 0; ks < 8; ++ks)
      kreg[ks] = *(const short8*)(kbb + ((size_t)(tn + w * 16 + ln)) * 256 + ks * 32 + qd * 8);
#pragma unroll
    for (int g = 0; g < 4; ++g) {
      const int q = g * 16 + ln;
      float p0 = __expf(S[g][0]), p1 = __expf(S[g][1]);
      float p2 = __expf(S[g][2]), p3 = __expf(S[g][3]);
      unsigned lo = (unsigned)to_bf(p0) | ((unsigned)to_bf(p1) << 16);
      unsigned hi = (unsigned)to_bf(p2) | ((unsigned)to_bf(p3) << 16);
      *(unsigned*)&pls[q * 68 + w * 16 + qd * 4] = lo;
      *(unsigned*)&pls[q * 68 + w * 16 + qd * 4 + 2] = hi;
      l_loc[g] += (p0 + p1) + (p2 + p3);
    }
    __syncthreads();  // P + V ready
#pragma unroll
    for (int kc = 0; kc < 2; ++kc) {
      short8 pf[4];
#pragma unroll
      for (int g = 0; g < 4; ++g)
        pf[g] = *(const short8*)&pls[(g * 16 + ln) * 68 + kc * 32 + qd * 8];
#pragma unroll
      for (int cs = 0; cs < 4; ++cs) {
        short8 vf = *(const short8*)&vls[(w * 64 + cs * 16 + ln) * 68 + kc * 32 + qd * 8];
#pragma unroll
        for (int g = 0; g < 4; ++g)
          O[g][cs] = __builtin_amdgcn_mfma_f32_16x16x32_bf16(vf, pf[g], O[g][cs], 0, 0, 0);
      }
    }
    __syncthreads();  // PV done
  }
#pragma unroll
  for (int g = 0; g < 4; ++g) {
    float lg = l_loc[g];
    lg += __shfl_xor(lg, 16, 64);
    lg += __shfl_xor(lg, 32, 64);
    if (qd == 0) lss[(g * 16 + ln) * 4 + w] = lg;
  }
  __syncthreads();
  const size_t prow = (size_t)z * 16384 + (size_t)b * 4096 + s0;
#pragma unroll
  for (int g = 0; g < 4; ++g) {
    short* pp = part + (prow + g * 16 + ln) * 256 + w * 64 + qd * 4;
#pragma unroll
    for (int cs = 0; cs < 4; ++cs) {
      short4v o4;
      o4[0] = (short)to_bf(O[g][cs][0]);
      o4[1] = (short)to_bf(O[g][cs][1]);
      o4[2] = (short)to_bf(O[g][cs][2]);
      o4[3] = (short)to_bf(O[g][cs][3]);
      *(short4v*)(pp + cs * 16) = o4;
    }
  }
  if (w == 0 && qd == 0) {
#pragma unroll
    for (int g = 0; g < 4; ++g) {
      const int q = g * 16 + ln;
      f32x4 lt = *(const f32x4*)&lss[q * 4];
      ml[(size_t)z * 16384 + (size_t)b * 4096 + s0 + q] =
          (lt[0] + lt[1]) + (lt[2] + lt[3]);
    }
  }
}

extern "C" void kernel_launch(void* const* d_in, const int* in_sizes, int n_in,
                              void* d_out, int out_size, void* d_ws, size_t ws_size,
                              hipStream_t stream) {
  const float* x       = (const float*)d_in[0];
  const float* te      = (const float*)d_in[1];
  const float* gn1_s   = (const float*)d_in[2];
  const float* gn1_b   = (const float*)d_in[3];
  const float* conv1_w = (const float*)d_in[4];
  const float* conv1_b = (const float*)d_in[5];
  const float* mlp_w   = (const float*)d_in[6];
  const float* mlp_b   = (const float*)d_in[7];
  const float* gn2_s   = (const float*)d_in[8];
  const float* gn2_b   = (const float*)d_in[9];
  const float* conv2_w = (const float*)d_in[10];
  const float* conv2_b = (const float*)d_in[11];
  const float* gnA_s   = (const float*)d_in[12];
  const float* gnA_b   = (const float*)d_in[13];
  const float* qkv_w   = (const float*)d_in[14];
  const float* out_w   = (const float*)d_in[15];
  const float* out_b   = (const float*)d_in[16];
  float* out = (float*)d_out;

  float* bufA  = (float*)d_ws;        // nT bf16 alias / attn partials (16MB)
  float* bufB  = bufA + NE;           // h1 fp32 [c][s] / attn partials (16MB)
  short* qb    = (short*)(bufB + NE); // G conv-input / q bf16 (8MB)
  short* kb    = qb + NE;             // Wt1+Wt2 / k bf16 (8MB)
  short* vb    = kb + NE;             // v bf16 (8MB)
  float* mlb   = (float*)(vb + NE);   // attn l: 4*16384 floats (256KB)
  float* stats = mlb + 65536;         // 3*256 raw-sum floats
  float* gbuf  = stats + 768;         // 2048 floats
  short* wqb   = (short*)(gbuf + 2048);   // qkv weights bf16 (384KB)
  short* wob   = wqb + 196608;            // proj weights bf16 (128KB)
  short* G     = qb;
  short* Wt1   = kb;
  short* Wt2   = Wt1 + 589824;
  short* nT    = (short*)bufA;        // GN(xr) bf16 [b][s][c]
  short* partb = (short*)bufA;        // attn partials bf16 [4][16384][256]

  // --- merged prep: weights + FiLM + gn1 raw stats + zero atomic stats ---
  prep_k<<<1673, 256, 0, stream>>>(conv1_w, conv2_w, qkv_w, out_w, te, mlp_w,
                                   mlp_b, x, Wt1, Wt2, wqb, wob, gbuf, stats);
  // --- ResNet block (convs fuse raw GN stats of their outputs) ---
  gn_t_k<1><<<1024, 256, 0, stream>>>(x, stats, gn1_s, gn1_b, G);
  conv_mfma_k<0><<<512, 256, 0, stream>>>(G, Wt1, conv1_b, gbuf, nullptr, bufB,
                                          stats + 256);
  gn_t_k<1><<<1024, 256, 0, stream>>>(bufB, stats + 256, gn2_s, gn2_b, G);
  conv_mfma_k<1><<<512, 256, 0, stream>>>(G, Wt2, conv2_b, nullptr, x, out,
                                          stats + 512);
  // --- Self-attention ---
  gn_t_k<0><<<1024, 256, 0, stream>>>(out, stats + 512, gnA_s, gnA_b, nT);
  gemm1x1_k<0><<<dim3(12, 16, 4), 256, 0, stream>>>(nT, wqb, nullptr, nullptr,
                                                    qb, kb, vb, nullptr);
  attn_k<<<1024, 256, 0, stream>>>(qb, kb, vb, partb, mlb);
  gemm1x1_k<1><<<dim3(4, 16, 4), 256, 0, stream>>>(partb, wob, out_b, mlb,
                                                   nullptr, nullptr, nullptr, out);
}

// Round 16
// 397.145 us; speedup vs baseline: 1.0779x; 1.0779x over previous
//
#include <hip/hip_runtime.h>
#include <math.h>

#define SS 4096      // H*W
#define NE 4194304   // B*C*H*W

typedef __attribute__((ext_vector_type(8))) short short8;
typedef __attribute__((ext_vector_type(4))) short short4v;
typedef __attribute__((ext_vector_type(4))) float f32x4;
typedef __attribute__((ext_vector_type(16))) float f32x16;

__device__ __forceinline__ float wave_sum(float v) {
#pragma unroll
  for (int off = 32; off > 0; off >>= 1) v += __shfl_xor(v, off, 64);
  return v;
}
__device__ __forceinline__ float silu_f(float y) { return y / (1.f + __expf(-y)); }

__device__ __forceinline__ unsigned short to_bf(float x) {
  union { float f; unsigned u; } v; v.f = x;
  unsigned r = v.u + 0x7FFFu + ((v.u >> 16) & 1u);
  return (unsigned short)(r >> 16);
}
__device__ __forceinline__ float bf2f(short s) {
  union { unsigned u; float f; } v;
  v.u = ((unsigned)(unsigned short)s) << 16;
  return v.f;
}

// ---------- GroupNorm stats (RAW sums; finalized in gn_t_k)
__global__ __launch_bounds__(256) void gn_stats_k(const float* __restrict__ x,
                                                  float* __restrict__ stats) {
  const float4* p = (const float4*)(x + (size_t)blockIdx.x * 32768);
  float s = 0.f, q = 0.f;
  for (int i = threadIdx.x; i < 8192; i += 256) {
    float4 v = p[i];
    s += v.x + v.y + v.z + v.w;
    q += v.x * v.x + v.y * v.y + v.z * v.z + v.w * v.w;
  }
  s = wave_sum(s); q = wave_sum(q);
  __shared__ float red[8];
  int wid = threadIdx.x >> 6;
  if ((threadIdx.x & 63) == 0) { red[wid] = s; red[wid + 4] = q; }
  __syncthreads();
  if (threadIdx.x == 0) {
    stats[blockIdx.x * 2] = red[0] + red[1] + red[2] + red[3];
    stats[blockIdx.x * 2 + 1] = red[4] + red[5] + red[6] + red[7];
  }
}

// ---------- fused GN (+ optional SiLU) + bf16 + transpose -> out[b][s][c]
// stats are RAW sums (s, sq); finalized inline.
template <int DO_SILU>
__global__ __launch_bounds__(256) void gn_t_k(const float* __restrict__ x,
    const float* __restrict__ stats, const float* __restrict__ sc,
    const float* __restrict__ bi, short* __restrict__ G) {
  __shared__ short T[64][72];
  const int tid = threadIdx.x;
  const int st = blockIdx.x & 63;
  const int ct = (blockIdx.x >> 6) & 3;
  const int b = blockIdx.x >> 8;
  const int s0 = st * 64, c0 = ct * 64;
#pragma unroll
  for (int r = 0; r < 4; ++r) {
    int idx = r * 256 + tid;
    int c_l = idx >> 4, s4 = idx & 15;
    int c = c0 + c_l;
    int sidx = (b * 32 + (c >> 3)) * 2;
    float ssum = stats[sidx], qsum = stats[sidx + 1];
    float m = ssum * (1.f / 32768.f);
    float var = qsum * (1.f / 32768.f) - m * m;
    float rs = rsqrtf(var + 1e-5f);
    float a = sc[c] * rs;
    float t = bi[c] - m * a;
    float4 v = *(const float4*)(x + ((size_t)(b * 256 + c)) * 4096 + s0 + s4 * 4);
    float o0 = v.x * a + t, o1 = v.y * a + t, o2 = v.z * a + t, o3 = v.w * a + t;
    if (DO_SILU) { o0 = silu_f(o0); o1 = silu_f(o1); o2 = silu_f(o2); o3 = silu_f(o3); }
    T[s4 * 4 + 0][c_l] = (short)to_bf(o0);
    T[s4 * 4 + 1][c_l] = (short)to_bf(o1);
    T[s4 * 4 + 2][c_l] = (short)to_bf(o2);
    T[s4 * 4 + 3][c_l] = (short)to_bf(o3);
  }
  __syncthreads();
#pragma unroll
  for (int r = 0; r < 2; ++r) {
    int idx = r * 256 + tid;
    int s_l = idx >> 3, cg = idx & 7;
    *(short8*)(G + ((size_t)(b * 4096 + s0 + s_l)) * 256 + c0 + cg * 8) =
        *(const short8*)&T[s_l][cg * 8];
  }
}

// ---------- merged prep: wprep x2 | wcast qkv | wcast out | FiLM |
// gn_stats(x) RAW (128 blks) -- x-stats have no deps, runs alongside prep.
__global__ __launch_bounds__(256) void prep_k(
    const float* __restrict__ conv1_w, const float* __restrict__ conv2_w,
    const float* __restrict__ qkv_w, const float* __restrict__ out_w,
    const float* __restrict__ te, const float* __restrict__ mlp_w,
    const float* __restrict__ mlp_b, const float* __restrict__ x,
    short* __restrict__ Wt1, short* __restrict__ Wt2, short* __restrict__ wqb,
    short* __restrict__ wob, float* __restrict__ gbuf,
    float* __restrict__ stats) {
  const int bid = blockIdx.x, tid = threadIdx.x;
  if (bid < 512) {
    __shared__ short L[9][256];
    const float* w = (bid < 256) ? conv1_w : conv2_w;
    short* wt = (bid < 256) ? Wt1 : Wt2;
    const int oc = bid & 255;
    const float* wp = w + (size_t)oc * 2304;
    for (int i = tid; i < 2304; i += 256) {
      int ic = i / 9, t = i - ic * 9;
      L[t][ic] = (short)to_bf(wp[i]);
    }
    __syncthreads();
    for (int i = tid; i < 2304; i += 256) {
      int t = i >> 8, ic = i & 255;
      wt[((size_t)(t * 256 + oc)) * 256 + ic] = L[t][ic];
    }
  } else if (bid < 1280) {
    int row = bid - 512;
    float sc = (row < 256) ? 0.0625f : 1.f;
    wqb[(size_t)row * 256 + tid] = (short)to_bf(qkv_w[(size_t)row * 256 + tid] * sc);
  } else if (bid < 1536) {
    int row = bid - 1280;
    wob[(size_t)row * 256 + tid] = (short)to_bf(out_w[(size_t)row * 256 + tid]);
  } else if (bid < 1544) {
    int t2 = (bid - 1536) * 256 + tid;
    int b = t2 >> 9, jj = t2 & 511;
    const float* tp = te + b * 256;
    const float* wp = mlp_w + jj * 256;
    float acc = mlp_b[jj];
    for (int t = 0; t < 256; ++t) acc += silu_f(tp[t]) * wp[t];
    gbuf[t2] = acc;
  } else {
    // gn_stats of x (raw sums) for one (b,group)
    const int sub = bid - 1544;
    const float4* p = (const float4*)(x + (size_t)sub * 32768);
    float s = 0.f, q = 0.f;
    for (int i = tid; i < 8192; i += 256) {
      float4 v = p[i];
      s += v.x + v.y + v.z + v.w;
      q += v.x * v.x + v.y * v.y + v.z * v.z + v.w * v.w;
    }
    s = wave_sum(s); q = wave_sum(q);
    __shared__ float red[8];
    int wid = tid >> 6;
    if ((tid & 63) == 0) { red[wid] = s; red[wid + 4] = q; }
    __syncthreads();
    if (tid == 0) {
      stats[sub * 2] = red[0] + red[1] + red[2] + red[3];
      stats[sub * 2 + 1] = red[4] + red[5] + red[6] + red[7];
    }
  }
}

__device__ __forceinline__ short8 ld2x4(const short* p) {
  short4v lo = *(const short4v*)p;
  short4v hi = *(const short4v*)(p + 4);
  short8 r;
  r[0] = lo[0]; r[1] = lo[1]; r[2] = lo[2]; r[3] = lo[3];
  r[4] = hi[0]; r[5] = hi[1]; r[6] = hi[2]; r[7] = hi[3];
  return r;
}

// ---------- MFMA 3x3 conv (R13: 512 blocks of 32oc x 256sp over 4 rows).
// NO fused output-stats: R14 measured +20us from epilogue wave_sum+atomics
// (contention on 256 hot floats at 1-block/CU tail) -- reverted.
template <int MODE>
__global__ __launch_bounds__(256, 1) void conv_mfma_k(
    const short* __restrict__ G, const short* __restrict__ Wt,
    const float* __restrict__ bias, const float* __restrict__ gb,
    const float* __restrict__ resid, float* __restrict__ out) {
  __shared__ __align__(16) short Xs[6][66][36];
  __shared__ __align__(16) short Ws[9][32][32];
  const int tid = threadIdx.x;
  const int oc0 = (blockIdx.x & 7) * 32;
  const int oy = ((blockIdx.x >> 3) & 15) * 4;
  const int b = blockIdx.x >> 7;
  const int wv = tid >> 6, lane = tid & 63;
  const int ln = lane & 31, hf = lane >> 5;

  f32x16 O0 = {}, O1 = {};

  for (int ic0 = 0; ic0 < 256; ic0 += 32) {
    __syncthreads();
    for (int i = tid; i < 1584; i += 256) {
      int r = i / 264;
      int rem = i - r * 264;
      int col = rem >> 2, g = rem & 3;
      int gy = oy + r - 1, gx = col - 1;
      short4v lo = {0, 0, 0, 0}, hi = {0, 0, 0, 0};
      if ((unsigned)gy < 64u && (unsigned)gx < 64u) {
        const short* gp = G + ((size_t)(b * 4096 + gy * 64 + gx)) * 256 + ic0 + g * 8;
        lo = *(const short4v*)gp;
        hi = *(const short4v*)(gp + 4);
      }
      *(short4v*)&Xs[r][col][g * 8] = lo;
      *(short4v*)&Xs[r][col][g * 8 + 4] = hi;
    }
    for (int i = tid; i < 1152; i += 256) {
      int t = i >> 7;
      int rem = i & 127;
      int o = rem >> 2, g = rem & 3;
      *(short8*)&Ws[t][o][g * 8] =
          *(const short8*)(Wt + ((size_t)(t * 256 + oc0 + o)) * 256 + ic0 + g * 8);
    }
    __syncthreads();
    for (int t = 0; t < 9; ++t) {
      const int dy = t / 3, dx = t - dy * 3;
      const short* xrow = &Xs[wv + dy][0][0];
#pragma unroll
      for (int ks = 0; ks < 2; ++ks) {
        short8 a0 = *(const short8*)&Ws[t][ln][ks * 16 + hf * 8];
        short8 b0 = ld2x4(xrow + (ln + dx) * 36 + ks * 16 + hf * 8);
        short8 b1 = ld2x4(xrow + (32 + ln + dx) * 36 + ks * 16 + hf * 8);
        O0 = __builtin_amdgcn_mfma_f32_32x32x16_bf16(a0, b0, O0, 0, 0, 0);
        O1 = __builtin_amdgcn_mfma_f32_32x32x16_bf16(a0, b1, O1, 0, 0, 0);
      }
    }
  }
  const int srow = (oy + wv) * 64;
#pragma unroll
  for (int i = 0; i < 16; ++i) {
    int oc = oc0 + (i & 3) + 8 * (i >> 2) + 4 * hf;
    float bi = bias[oc];
    size_t base = ((size_t)(b * 256 + oc)) * 4096 + srow;
    float v0 = O0[i] + bi, v1 = O1[i] + bi;
    if (MODE == 0) {
      float ga = 1.f + gb[b * 512 + oc], be = gb[b * 512 + 256 + oc];
      v0 = ga * v0 + be;
      v1 = ga * v1 + be;
    } else {
      v0 += resid[base + ln];
      v1 += resid[base + 32 + ln];
    }
    out[base + ln] = v0;
    out[base + 32 + ln] = v1;
  }
}

// ---------- 1x1 GEMM (MFMA)
template <int MODE>
__global__ __launch_bounds__(256, 2) void gemm1x1_k(
    const short* __restrict__ X, const short* __restrict__ W,
    const float* __restrict__ bias, const float* __restrict__ ml,
    short* __restrict__ q, short* __restrict__ k, short* __restrict__ v,
    float* __restrict__ out) {
  __shared__ __align__(16) short sh[18432];
  const int tid = threadIdx.x;
  const int o0 = blockIdx.x * 64;
  const int s0 = blockIdx.y * 256;
  const int b = blockIdx.z;
  const int w = tid >> 6, lane = tid & 63, ln = lane & 31, hf = lane >> 5;
  {
    const int o = tid >> 2, g = tid & 3;
#pragma unroll
    for (int j = 0; j < 8; ++j) {
      int c = (g * 8 + j) * 8;
      *(short8*)&sh[o * 264 + c] = *(const short8*)(W + (size_t)(o0 + o) * 256 + c);
    }
  }
  __syncthreads();
  f32x16 acc[2][2] = {{{}, {}}, {{}, {}}};
  if (MODE == 0) {
    const short* xp = X + ((size_t)(b * 4096 + s0 + w * 64)) * 256;
    short8 bf0 = *(const short8*)(xp + (size_t)ln * 256 + hf * 8);
    short8 bf1 = *(const short8*)(xp + (size_t)(32 + ln) * 256 + hf * 8);
#pragma unroll
    for (int ks = 0; ks < 16; ++ks) {
      short8 a0 = *(const short8*)&sh[ln * 264 + ks * 16 + hf * 8];
      short8 a1 = *(const short8*)&sh[(32 + ln) * 264 + ks * 16 + hf * 8];
      short8 nb0 = bf0, nb1 = bf1;
      if (ks < 15) {
        nb0 = *(const short8*)(xp + (size_t)ln * 256 + (ks + 1) * 16 + hf * 8);
        nb1 = *(const short8*)(xp + (size_t)(32 + ln) * 256 + (ks + 1) * 16 + hf * 8);
      }
      acc[0][0] = __builtin_amdgcn_mfma_f32_32x32x16_bf16(a0, bf0, acc[0][0], 0, 0, 0);
      acc[0][1] = __builtin_amdgcn_mfma_f32_32x32x16_bf16(a0, bf1, acc[0][1], 0, 0, 0);
      acc[1][0] = __builtin_amdgcn_mfma_f32_32x32x16_bf16(a1, bf0, acc[1][0], 0, 0, 0);
      acc[1][1] = __builtin_amdgcn_mfma_f32_32x32x16_bf16(a1, bf1, acc[1][1], 0, 0, 0);
      bf0 = nb0; bf1 = nb1;
    }
  } else {
    const size_t r0 = (size_t)b * 4096 + s0 + w * 64 + ln;
    const size_t r1 = r0 + 32;
    float inv0 = 1.f / (ml[r0] + ml[16384 + r0] + ml[32768 + r0] + ml[49152 + r0]);
    float inv1 = 1.f / (ml[r1] + ml[16384 + r1] + ml[32768 + r1] + ml[49152 + r1]);
#pragma unroll 4
    for (int ks = 0; ks < 16; ++ks) {
      float t0[8] = {0, 0, 0, 0, 0, 0, 0, 0}, t1[8] = {0, 0, 0, 0, 0, 0, 0, 0};
#pragma unroll
      for (int z = 0; z < 4; ++z) {
        short8 p0 = *(const short8*)(X + ((size_t)z * 16384 + r0) * 256 + ks * 16 + hf * 8);
        short8 p1 = *(const short8*)(X + ((size_t)z * 16384 + r1) * 256 + ks * 16 + hf * 8);
#pragma unroll
        for (int jj = 0; jj < 8; ++jj) { t0[jj] += bf2f(p0[jj]); t1[jj] += bf2f(p1[jj]); }
      }
      short8 bf0, bf1;
#pragma unroll
      for (int jj = 0; jj < 8; ++jj) {
        bf0[jj] = (short)to_bf(t0[jj] * inv0);
        bf1[jj] = (short)to_bf(t1[jj] * inv1);
      }
      short8 a0 = *(const short8*)&sh[ln * 264 + ks * 16 + hf * 8];
      short8 a1 = *(const short8*)&sh[(32 + ln) * 264 + ks * 16 + hf * 8];
      acc[0][0] = __builtin_amdgcn_mfma_f32_32x32x16_bf16(a0, bf0, acc[0][0], 0, 0, 0);
      acc[0][1] = __builtin_amdgcn_mfma_f32_32x32x16_bf16(a0, bf1, acc[0][1], 0, 0, 0);
      acc[1][0] = __builtin_amdgcn_mfma_f32_32x32x16_bf16(a1, bf0, acc[1][0], 0, 0, 0);
      acc[1][1] = __builtin_amdgcn_mfma_f32_32x32x16_bf16(a1, bf1, acc[1][1], 0, 0, 0);
    }
  }
  if (MODE == 1) {
#pragma unroll
    for (int os = 0; os < 2; ++os)
#pragma unroll
      for (int ss = 0; ss < 2; ++ss)
#pragma unroll
        for (int i = 0; i < 16; ++i) {
          int oc = o0 + os * 32 + (i & 3) + 8 * (i >> 2) + 4 * hf;
          size_t idx = ((size_t)(b * 256 + oc)) * 4096 + s0 + w * 64 + ss * 32 + ln;
          out[idx] = out[idx] + acc[os][ss][i] + bias[oc];
        }
  } else if (o0 >= 512) {
#pragma unroll
    for (int os = 0; os < 2; ++os)
#pragma unroll
      for (int ss = 0; ss < 2; ++ss)
#pragma unroll
        for (int i = 0; i < 16; ++i) {
          int oc = (o0 - 512) + os * 32 + (i & 3) + 8 * (i >> 2) + 4 * hf;
          v[((size_t)(b * 256 + oc)) * 4096 + s0 + w * 64 + ss * 32 + ln] =
              (short)to_bf(acc[os][ss][i]);
        }
  } else {
    __syncthreads();
#pragma unroll
    for (int os = 0; os < 2; ++os)
#pragma unroll
      for (int ss = 0; ss < 2; ++ss)
#pragma unroll
        for (int i = 0; i < 16; ++i) {
          int o_l = os * 32 + (i & 3) + 8 * (i >> 2) + 4 * hf;
          int s_l = ss * 32 + ln;
          sh[(w * 64 + s_l) * 72 + o_l] = (short)to_bf(acc[os][ss][i]);
        }
    __syncthreads();
    short* dst = (o0 < 256) ? q : k;
    const int co = (o0 < 256) ? o0 : o0 - 256;
    const short* src = &sh[(w * 64 + lane) * 72];
    short* gp = dst + ((size_t)(b * 4096 + s0 + w * 64 + lane)) * 256 + co;
#pragma unroll
    for (int j = 0; j < 8; ++j)
      *(short8*)(gp + j * 8) = *(const short8*)(src + j * 8);
  }
}

// ---------- MFMA flash attention (R9/R13, measured 108us): 16x16x32,
// q-tile 64, Q in LDS (pad 268), V staged via LDS, K direct from global.
// KEEP (256,2): >=3 spills (R4/R5). 32x32 variants were L2-request-bound.
__global__ __launch_bounds__(256, 2) void attn_k(const short* __restrict__ qb,
    const short* __restrict__ kb, const short* __restrict__ vb,
    short* __restrict__ part, float* __restrict__ ml) {
  __shared__ __align__(16) short qls[64 * 268];
  __shared__ __align__(16) short vls[256 * 68];
  __shared__ __align__(16) short pls[64 * 68];
  __shared__ __align__(16) float lss[64 * 4];
  const int tid = threadIdx.x;
  const int j = blockIdx.x & 7;
  const int b = j >> 1;
  const int idx = ((blockIdx.x >> 3) << 1) | (j & 1);  // 0..255
  const int z = idx >> 6;
  const int s0 = (idx & 63) * 64;
  const int kv0 = z * 1024;
  const int w = tid >> 6, lane = tid & 63, ln = lane & 15, qd = lane >> 4;

  {
    const short* qsrc = qb + ((size_t)(b * 4096 + s0)) * 256;
    for (int i = tid; i < 2048; i += 256) {
      int r = i >> 5, cc = i & 31;
      *(short8*)&qls[r * 268 + cc * 8] = *(const short8*)(qsrc + (size_t)r * 256 + cc * 8);
    }
  }
  const f32x4 z4 = {0.f, 0.f, 0.f, 0.f};
  f32x4 O[4][4];
#pragma unroll
  for (int g = 0; g < 4; ++g)
#pragma unroll
    for (int cs = 0; cs < 4; ++cs) O[g][cs] = z4;
  float l_loc[4] = {0.f, 0.f, 0.f, 0.f};

  const short* kbb = kb + ((size_t)(b * 4096 + kv0)) * 256;
  const short* vbb = vb + ((size_t)b * 256) * 4096 + kv0;

  const int vr = tid >> 3;
  const int vc = (tid & 7) * 8;

  short8 kreg[8], vreg[8];
#pragma unroll
  for (int ks = 0; ks < 8; ++ks)
    kreg[ks] = *(const short8*)(kbb + ((size_t)(w * 16 + ln)) * 256 + ks * 32 + qd * 8);
#pragma unroll
  for (int p = 0; p < 8; ++p)
    vreg[p] = *(const short8*)(vbb + ((size_t)(vr + p * 32)) * 4096 + vc);
  __syncthreads();  // Q staged

  for (int t0 = 0; t0 < 1024; t0 += 64) {
    const int tn = (t0 + 64 < 1024) ? t0 + 64 : t0;
#pragma unroll
    for (int p = 0; p < 8; ++p)
      *(short8*)&vls[(vr + p * 32) * 68 + vc] = vreg[p];
#pragma unroll
    for (int p = 0; p < 8; ++p)
      vreg[p] = *(const short8*)(vbb + ((size_t)(vr + p * 32)) * 4096 + tn + vc);
    f32x4 S[4] = {z4, z4, z4, z4};
#pragma unroll
    for (int ks = 0; ks < 8; ++ks) {
#pragma unroll
      for (int g = 0; g < 4; ++g) {
        short8 qf = *(const short8*)&qls[(g * 16 + ln) * 268 + ks * 32 + qd * 8];
        S[g] = __builtin_amdgcn_mfma_f32_16x16x32_bf16(kreg[ks], qf, S[g], 0, 0, 0);
      }
    }
#pragma unroll
    for (int ks = 0; ks < 8; ++ks)
      kreg[ks] = *(const short8*)(kbb + ((size_t)(tn + w * 16 + ln)) * 256 + ks * 32 + qd * 8);
#pragma unroll
    for (int g = 0; g < 4; ++g) {
      const int q = g * 16 + ln;
      float p0 = __expf(S[g][0]), p1 = __expf(S[g][1]);
      float p2 = __expf(S[g][2]), p3 = __expf(S[g][3]);
      unsigned lo = (unsigned)to_bf(p0) | ((unsigned)to_bf(p1) << 16);
      unsigned hi = (unsigned)to_bf(p2) | ((unsigned)to_bf(p3) << 16);
      *(unsigned*)&pls[q * 68 + w * 16 + qd * 4] = lo;
      *(unsigned*)&pls[q * 68 + w * 16 + qd * 4 + 2] = hi;
      l_loc[g] += (p0 + p1) + (p2 + p3);
    }
    __syncthreads();  // P + V ready
#pragma unroll
    for (int kc = 0; kc < 2; ++kc) {
      short8 pf[4];
#pragma unroll
      for (int g = 0; g < 4; ++g)
        pf[g] = *(const short8*)&pls[(g * 16 + ln) * 68 + kc * 32 + qd * 8];
#pragma unroll
      for (int cs = 0; cs < 4; ++cs) {
        short8 vf = *(const short8*)&vls[(w * 64 + cs * 16 + ln) * 68 + kc * 32 + qd * 8];
#pragma unroll
        for (int g = 0; g < 4; ++g)
          O[g][cs] = __builtin_amdgcn_mfma_f32_16x16x32_bf16(vf, pf[g], O[g][cs], 0, 0, 0);
      }
    }
    __syncthreads();  // PV done
  }
#pragma unroll
  for (int g = 0; g < 4; ++g) {
    float lg = l_loc[g];
    lg += __shfl_xor(lg, 16, 64);
    lg += __shfl_xor(lg, 32, 64);
    if (qd == 0) lss[(g * 16 + ln) * 4 + w] = lg;
  }
  __syncthreads();
  const size_t prow = (size_t)z * 16384 + (size_t)b * 4096 + s0;
#pragma unroll
  for (int g = 0; g < 4; ++g) {
    short* pp = part + (prow + g * 16 + ln) * 256 + w * 64 + qd * 4;
#pragma unroll
    for (int cs = 0; cs < 4; ++cs) {
      short4v o4;
      o4[0] = (short)to_bf(O[g][cs][0]);
      o4[1] = (short)to_bf(O[g][cs][1]);
      o4[2] = (short)to_bf(O[g][cs][2]);
      o4[3] = (short)to_bf(O[g][cs][3]);
      *(short4v*)(pp + cs * 16) = o4;
    }
  }
  if (w == 0 && qd == 0) {
#pragma unroll
    for (int g = 0; g < 4; ++g) {
      const int q = g * 16 + ln;
      f32x4 lt = *(const f32x4*)&lss[q * 4];
      ml[(size_t)z * 16384 + (size_t)b * 4096 + s0 + q] =
          (lt[0] + lt[1]) + (lt[2] + lt[3]);
    }
  }
}

extern "C" void kernel_launch(void* const* d_in, const int* in_sizes, int n_in,
                              void* d_out, int out_size, void* d_ws, size_t ws_size,
                              hipStream_t stream) {
  const float* x       = (const float*)d_in[0];
  const float* te      = (const float*)d_in[1];
  const float* gn1_s   = (const float*)d_in[2];
  const float* gn1_b   = (const float*)d_in[3];
  const float* conv1_w = (const float*)d_in[4];
  const float* conv1_b = (const float*)d_in[5];
  const float* mlp_w   = (const float*)d_in[6];
  const float* mlp_b   = (const float*)d_in[7];
  const float* gn2_s   = (const float*)d_in[8];
  const float* gn2_b   = (const float*)d_in[9];
  const float* conv2_w = (const float*)d_in[10];
  const float* conv2_b = (const float*)d_in[11];
  const float* gnA_s   = (const float*)d_in[12];
  const float* gnA_b   = (const float*)d_in[13];
  const float* qkv_w   = (const float*)d_in[14];
  const float* out_w   = (const float*)d_in[15];
  const float* out_b   = (const float*)d_in[16];
  float* out = (float*)d_out;

  float* bufA  = (float*)d_ws;        // nT bf16 alias / attn partials (16MB)
  float* bufB  = bufA + NE;           // h1 fp32 [c][s] / attn partials (16MB)
  short* qb    = (short*)(bufB + NE); // G conv-input / q bf16 (8MB)
  short* kb    = qb + NE;             // Wt1+Wt2 / k bf16 (8MB)
  short* vb    = kb + NE;             // v bf16 (8MB)
  float* mlb   = (float*)(vb + NE);   // attn l: 4*16384 floats (256KB)
  float* stats = mlb + 65536;         // 3*256 raw-sum floats
  float* gbuf  = stats + 768;         // 2048 floats
  short* wqb   = (short*)(gbuf + 2048);   // qkv weights bf16 (384KB)
  short* wob   = wqb + 196608;            // proj weights bf16 (128KB)
  short* G     = qb;
  short* Wt1   = kb;
  short* Wt2   = Wt1 + 589824;
  short* nT    = (short*)bufA;        // GN(xr) bf16 [b][s][c]
  short* partb = (short*)bufA;        // attn partials bf16 [4][16384][256]

  // --- merged prep: weights + FiLM + gn1 raw stats ---
  prep_k<<<1672, 256, 0, stream>>>(conv1_w, conv2_w, qkv_w, out_w, te, mlp_w,
                                   mlp_b, x, Wt1, Wt2, wqb, wob, gbuf, stats);
  // --- ResNet block ---
  gn_t_k<1><<<1024, 256, 0, stream>>>(x, stats, gn1_s, gn1_b, G);
  conv_mfma_k<0><<<512, 256, 0, stream>>>(G, Wt1, conv1_b, gbuf, nullptr, bufB);
  gn_stats_k<<<128, 256, 0, stream>>>(bufB, stats + 256);
  gn_t_k<1><<<1024, 256, 0, stream>>>(bufB, stats + 256, gn2_s, gn2_b, G);
  conv_mfma_k<1><<<512, 256, 0, stream>>>(G, Wt2, conv2_b, nullptr, x, out);
  // --- Self-attention ---
  gn_stats_k<<<128, 256, 0, stream>>>(out, stats + 512);
  gn_t_k<0><<<1024, 256, 0, stream>>>(out, stats + 512, gnA_s, gnA_b, nT);
  gemm1x1_k<0><<<dim3(12, 16, 4), 256, 0, stream>>>(nT, wqb, nullptr, nullptr,
                                                    qb, kb, vb, nullptr);
  attn_k<<<1024, 256, 0, stream>>>(qb, kb, vb, partb, mlb);
  gemm1x1_k<1><<<dim3(4, 16, 4), 256, 0, stream>>>(partb, wob, out_b, mlb,
                                                   nullptr, nullptr, nullptr, out);
}